// Round 1
// baseline (137.151 us; speedup 1.0000x reference)
//
#include <hip/hip_runtime.h>

// ForegroundSelectorForMask: per row, pick first 512 foreground indices
// (class_targets > 0) in ascending order (== jax.lax.top_k on {0,1} with
// stable tie-break), padding with first background indices if < 512 fg.
// Then gather class_targets, box_targets, boxes, proposal_to_label_map.
//
// B=256 rows, N=16384 proposals, K=512 selected.
// Outputs concatenated flat as float32:
//   [0,              B*K)      fg_class_targets
//   [B*K,            B*K*5)    fg_box_targets (B,K,4)
//   [B*K*5,          B*K*9)    fg_boxes       (B,K,4)
//   [B*K*9,          B*K*10)   fg_label_map

#define NUM_B 256
#define NUM_N 16384
#define KFG   512
#define BLOCK 1024
#define NWAVE (BLOCK / 64)

__global__ __launch_bounds__(BLOCK) void fg_select_kernel(
    const int*    __restrict__ cls,
    const float4* __restrict__ box_t,
    const float4* __restrict__ boxes,
    const int*    __restrict__ lmap,
    float*        __restrict__ out)
{
    const int b    = blockIdx.x;
    const int tid  = threadIdx.x;
    const int lane = tid & 63;
    const int wid  = tid >> 6;

    __shared__ int fg_idx[KFG];
    __shared__ int wcnt[NWAVE];

    const long long row = (long long)b * NUM_N;

    // ---- Pass 1: stable compaction of foreground indices (early exit) ----
    int base = 0;  // running fg count; identical across all threads
    for (int chunk = 0; chunk < NUM_N; chunk += BLOCK) {
        const int i    = chunk + tid;
        const int flag = cls[row + i] > 0;
        const unsigned long long bal = __ballot(flag);
        const int lpre = __popcll(bal & ((1ull << lane) - 1ull));
        if (lane == 0) wcnt[wid] = __popcll(bal);
        __syncthreads();
        int woff = 0, ctotal = 0;
        #pragma unroll
        for (int w = 0; w < NWAVE; ++w) {
            const int c = wcnt[w];
            if (w < wid) woff += c;
            ctotal += c;
        }
        const int pos = base + woff + lpre;
        if (flag && pos < KFG) fg_idx[pos] = i;
        base += ctotal;
        __syncthreads();  // protects wcnt reuse AND makes break uniform-safe
        if (base >= KFG) break;  // ~always after first chunk (P(fg)≈0.989)
    }

    // ---- Pass 2 (rare): pad with first background indices ----
    if (base < KFG) {
        const int fgc = base;
        int bbase = 0;
        for (int chunk = 0; chunk < NUM_N; chunk += BLOCK) {
            const int i    = chunk + tid;
            const int flag = cls[row + i] == 0;
            const unsigned long long bal = __ballot(flag);
            const int lpre = __popcll(bal & ((1ull << lane) - 1ull));
            if (lane == 0) wcnt[wid] = __popcll(bal);
            __syncthreads();
            int woff = 0, ctotal = 0;
            #pragma unroll
            for (int w = 0; w < NWAVE; ++w) {
                const int c = wcnt[w];
                if (w < wid) woff += c;
                ctotal += c;
            }
            const int pos = fgc + bbase + woff + lpre;
            if (flag && pos < KFG) fg_idx[pos] = i;
            bbase += ctotal;
            __syncthreads();
            if (fgc + bbase >= KFG) break;
        }
    }
    __syncthreads();

    // ---- Gather + write: threads 0..511, one selected index each ----
    if (tid < KFG) {
        const int k         = tid;
        const int idx       = fg_idx[k];
        const long long src = row + idx;
        const long long ok  = (long long)b * KFG + k;

        out[ok] = (float)cls[src];                                      // class
        ((float4*)(out + (long long)NUM_B * KFG    ))[ok] = box_t[src]; // box_targets
        ((float4*)(out + (long long)NUM_B * KFG * 5))[ok] = boxes[src]; // boxes
        out[(long long)NUM_B * KFG * 9 + ok] = (float)lmap[src];        // label_map
    }
}

extern "C" void kernel_launch(void* const* d_in, const int* in_sizes, int n_in,
                              void* d_out, int out_size, void* d_ws, size_t ws_size,
                              hipStream_t stream) {
    const int*    cls = (const int*)d_in[0];
    const float4* bt  = (const float4*)d_in[1];
    const float4* bx  = (const float4*)d_in[2];
    const int*    lm  = (const int*)d_in[3];
    float*        out = (float*)d_out;

    fg_select_kernel<<<NUM_B, BLOCK, 0, stream>>>(cls, bt, bx, lm, out);
}

// Round 2
// 137.019 us; speedup vs baseline: 1.0010x; 1.0010x over previous
//
#include <hip/hip_runtime.h>

// ForegroundSelectorForMask: per row, pick first 512 foreground indices
// (class_targets > 0) in ascending order (== jax.lax.top_k on {0,1} with
// stable tie-break), padding with first background indices if < 512 fg.
// Then gather class_targets, box_targets, boxes, proposal_to_label_map.
//
// B=256 rows, N=16384 proposals, K=512 selected.
// Outputs concatenated flat as float32:
//   [0,              B*K)      fg_class_targets
//   [B*K,            B*K*5)    fg_box_targets (B,K,4)
//   [B*K*5,          B*K*9)    fg_boxes       (B,K,4)
//   [B*K*9,          B*K*10)   fg_label_map

#define NUM_B 256
#define NUM_N 16384
#define KFG   512
#define BLOCK 1024
#define NWAVE (BLOCK / 64)

__global__ __launch_bounds__(BLOCK) void fg_select_kernel(
    const int*    __restrict__ cls,
    const float4* __restrict__ box_t,
    const float4* __restrict__ boxes,
    const int*    __restrict__ lmap,
    float*        __restrict__ out)
{
    const int b    = blockIdx.x;
    const int tid  = threadIdx.x;
    const int lane = tid & 63;
    const int wid  = tid >> 6;

    __shared__ int   fg_idx[KFG];
    __shared__ float fg_cls[KFG];   // class value captured at selection time
    __shared__ int   wcnt[NWAVE];

    const long long row = (long long)b * NUM_N;

    // ---- Pass 1: stable compaction of foreground indices (early exit) ----
    int base = 0;  // running fg count; identical across all threads
    for (int chunk = 0; chunk < NUM_N; chunk += BLOCK) {
        const int i = chunk + tid;
        const int c = cls[row + i];
        const int flag = c > 0;
        const unsigned long long bal = __ballot(flag);
        const int lpre = __popcll(bal & ((1ull << lane) - 1ull));
        if (lane == 0) wcnt[wid] = __popcll(bal);
        __syncthreads();
        int woff = 0, ctotal = 0;
        #pragma unroll
        for (int w = 0; w < NWAVE; ++w) {
            const int cnt = wcnt[w];
            if (w < wid) woff += cnt;
            ctotal += cnt;
        }
        const int pos = base + woff + lpre;
        if (flag && pos < KFG) {
            fg_idx[pos] = i;
            fg_cls[pos] = (float)c;   // no re-gather of class later
        }
        base += ctotal;
        __syncthreads();  // protects wcnt reuse AND makes break uniform-safe
        if (base >= KFG) break;  // ~always after first chunk (P(fg)≈0.989)
    }

    // ---- Pass 2 (rare): pad with first background indices (class == 0) ----
    if (base < KFG) {
        const int fgc = base;
        int bbase = 0;
        for (int chunk = 0; chunk < NUM_N; chunk += BLOCK) {
            const int i    = chunk + tid;
            const int flag = cls[row + i] == 0;
            const unsigned long long bal = __ballot(flag);
            const int lpre = __popcll(bal & ((1ull << lane) - 1ull));
            if (lane == 0) wcnt[wid] = __popcll(bal);
            __syncthreads();
            int woff = 0, ctotal = 0;
            #pragma unroll
            for (int w = 0; w < NWAVE; ++w) {
                const int cnt = wcnt[w];
                if (w < wid) woff += cnt;
                ctotal += cnt;
            }
            const int pos = fgc + bbase + woff + lpre;
            if (flag && pos < KFG) {
                fg_idx[pos] = i;
                fg_cls[pos] = 0.0f;   // background class is 0 by definition
            }
            bbase += ctotal;
            __syncthreads();
            if (fgc + bbase >= KFG) break;
        }
    }
    __syncthreads();

    // ---- Gather + write: all 1024 threads, 2 halves ----
    const long long bK = (long long)b * KFG;
    if (tid < KFG) {
        const int k   = tid;
        const int idx = fg_idx[k];
        out[bK + k] = fg_cls[k];                                        // class (LDS)
        ((float4*)(out + (long long)NUM_B * KFG))[bK + k] = box_t[row + idx];  // box_targets
    } else {
        const int k   = tid - KFG;
        const int idx = fg_idx[k];
        ((float4*)(out + (long long)NUM_B * KFG * 5))[bK + k] = boxes[row + idx]; // boxes
        out[(long long)NUM_B * KFG * 9 + bK + k] = (float)lmap[row + idx];        // label_map
    }
}

extern "C" void kernel_launch(void* const* d_in, const int* in_sizes, int n_in,
                              void* d_out, int out_size, void* d_ws, size_t ws_size,
                              hipStream_t stream) {
    const int*    cls = (const int*)d_in[0];
    const float4* bt  = (const float4*)d_in[1];
    const float4* bx  = (const float4*)d_in[2];
    const int*    lm  = (const int*)d_in[3];
    float*        out = (float*)d_out;

    fg_select_kernel<<<NUM_B, BLOCK, 0, stream>>>(cls, bt, bx, lm, out);
}